// Round 22
// baseline (50.935 us; speedup 1.0000x reference)
//
#include <hip/hip_runtime.h>

namespace {
constexpr int Wd = 160, Hd = 192, Dd = 160, Bd = 2;
constexpr int HW = Hd * Wd;
constexpr int THREADS = 128;               // 2 waves -> narrow barrier domain
constexpr int ROWS_OUT = 6;                // output rows per block
constexpr int ROWS_LDS = 8;                // staged rows incl. h-halo
constexpr int TILE_W = 80;                 // w-split: 2 segments
constexpr int STRIPS = TILE_W / 4;         // 20
constexpr int RS = 84;                     // fp16 row stride (halves); 168B/row
constexpr int CTHREADS = ROWS_OUT * STRIPS;   // 120 compute threads
constexpr int TASKS = 2 * ROWS_LDS * STRIPS;  // 320 staging tasks
constexpr int WSEG = Wd / TILE_W;          // 2
constexpr int DCHUNK = 10;
constexpr int NCHUNK = Dd / DCHUNK;        // 16
constexpr int RGROUPS = Hd / ROWS_OUT;     // 32
// grid = 64 x 16 x 2 = 2048 blocks = 8 blocks/CU (2 waves each)
constexpr float EPS = 1e-8f;
}

using v4f = __attribute__((ext_vector_type(4))) float;
using v4h = __attribute__((ext_vector_type(4))) _Float16;

__device__ __forceinline__ float dpp_up1(float v) {   // lane i <- lane i-1
  return __int_as_float(__builtin_amdgcn_update_dpp(
      0, __float_as_int(v), 0x138, 0xF, 0xF, true));  // wave_shr:1
}
__device__ __forceinline__ float dpp_dn1(float v) {   // lane i <- lane i+1
  return __int_as_float(__builtin_amdgcn_update_dpp(
      0, __float_as_int(v), 0x130, 0xF, 0xF, true));  // wave_shl:1
}

__global__ __launch_bounds__(THREADS) void sobel_loss_kernel(
    const float* __restrict__ pred, const float* __restrict__ targ,
    float* __restrict__ out) {
  // staged separable row partials in fp16: sw = [1,2,1]_w*x, dw = [-1,0,1]_w*x
  __shared__ __align__(16) _Float16 lsw[2][ROWS_LDS][RS];   // 2.6 KB
  __shared__ __align__(16) _Float16 ldw[2][ROWS_LDS][RS];   // 2.6 KB
  const int tid = threadIdx.x;
  const int lane = tid & 63;
  const int wseg = blockIdx.x & 1;
  const int h0 = (blockIdx.x >> 1) * ROWS_OUT;
  const int wb = wseg * TILE_W;
  const int d0 = blockIdx.y * DCHUNK;
  const size_t volOff = (size_t)blockIdx.z * Dd * HW;
  const float* pb = pred + volOff;
  const float* tb = targ + volOff;

  // ---- staging task decode (2.5 tasks/thread, loop-invariant) ----
  const float* gs[3];
  _Float16* psw[3];
  _Float16* pdw[3];
  bool sok[3], rok[3], zL[3], zR[3], pL[3], pR[3];
#pragma unroll
  for (int u = 0; u < 3; ++u) {
    const int i = tid + THREADS * u;
    const bool ok = (i < TASKS);
    const int ic = ok ? i : 0;
    const int t_ = ic / (ROWS_LDS * STRIPS);
    const int rem = ic - t_ * (ROWS_LDS * STRIPS);
    const int r8 = rem / STRIPS, s = rem - r8 * STRIPS;
    const int hh = h0 - 1 + r8;
    const bool rv = ok && ((unsigned)hh < (unsigned)Hd);
    sok[u] = ok;
    rok[u] = rv;
    zL[u] = (s == 0) && (wb == 0);
    zR[u] = (s == STRIPS - 1) && (wb + TILE_W >= Wd);
    pL[u] = ok && (((s == 0) && (wb > 0)) || ((s != 0) && (lane == 0)));
    pR[u] = ok && (((s == STRIPS - 1) && (wb + TILE_W < Wd)) ||
                   ((s != STRIPS - 1) && (lane == 63)));
    gs[u] = (t_ ? tb : pb) + (size_t)(rv ? hh : 0) * Wd + wb + s * 4;
    psw[u] = &lsw[t_][r8][s * 4];
    pdw[u] = &ldw[t_][r8][s * 4];
  }

  float4 m[3];
  float hl[3], hr[3];
  auto GLOAD = [&](int d) {   // float4-only + exec-masked edge scalars
    const bool dok = (unsigned)d < (unsigned)Dd;
    const size_t so = (size_t)d * HW;
#pragma unroll
    for (int u = 0; u < 3; ++u) {
      float4 v = make_float4(0.f, 0.f, 0.f, 0.f);
      float a = 0.f, b = 0.f;
      if (dok && rok[u]) {
        v = *reinterpret_cast<const float4*>(gs[u] + so);
        if (pL[u]) a = gs[u][so - 1];
        if (pR[u]) b = gs[u][so + 4];
      }
      m[u] = v; hl[u] = a; hr[u] = b;
    }
  };

  auto STAGE = [&]() {   // w-conv in f32, convert, write fp16 sw/dw (b64)
#pragma unroll
    for (int u = 0; u < 3; ++u) {
      float xl = dpp_up1(m[u].w);          // lane-1 holds x[4s-4..4s-1]
      float xr = dpp_dn1(m[u].x);          // lane+1 holds x[4s+4..4s+7]
      if (zL[u]) xl = 0.f;
      if (pL[u]) xl = hl[u];
      if (zR[u]) xr = 0.f;
      if (pR[u]) xr = hr[u];
      const float x0 = xl, x1 = m[u].x, x2 = m[u].y, x3 = m[u].z,
                  x4 = m[u].w, x5 = xr;
      v4f swf, dwf;
      swf[0] = fmaf(2.f, x1, x0 + x2);  dwf[0] = x2 - x0;
      swf[1] = fmaf(2.f, x2, x1 + x3);  dwf[1] = x3 - x1;
      swf[2] = fmaf(2.f, x3, x2 + x4);  dwf[2] = x4 - x2;
      swf[3] = fmaf(2.f, x4, x3 + x5);  dwf[3] = x5 - x3;
      if (sok[u]) {
        *reinterpret_cast<v4h*>(psw[u]) = __builtin_convertvector(swf, v4h);
        *reinterpret_cast<v4h*>(pdw[u]) = __builtin_convertvector(dwf, v4h);
      }
    }
  };

  // ---- compute decode: output row cr (0..5), strip cs (0..19) ----
  const int cr = tid / STRIPS;
  const int cs4 = (tid - cr * STRIPS) * 4;
  const bool is_c = (tid < CTHREADS);

  // rolling state [slot][tensor] as packed fp16 -> v_pk_*_f16 math
  v4h A[3][2], B[3][2], C[3][2];
  const _Float16 h2 = (_Float16)2.0f;

  auto HCONV = [&](int slot) {
#pragma unroll
    for (int t_ = 0; t_ < 2; ++t_) {
      const v4h sm = *reinterpret_cast<const v4h*>(&lsw[t_][cr][cs4]);
      const v4h s0 = *reinterpret_cast<const v4h*>(&lsw[t_][cr + 1][cs4]);
      const v4h sp = *reinterpret_cast<const v4h*>(&lsw[t_][cr + 2][cs4]);
      const v4h dm = *reinterpret_cast<const v4h*>(&ldw[t_][cr][cs4]);
      const v4h dd = *reinterpret_cast<const v4h*>(&ldw[t_][cr + 1][cs4]);
      const v4h dp = *reinterpret_cast<const v4h*>(&ldw[t_][cr + 2][cs4]);
      A[slot][t_] = s0 * h2 + (sm + sp);
      B[slot][t_] = dd * h2 + (dm + dp);
      C[slot][t_] = sp - sm;
    }
  };

  v4f accv = {0.f, 0.f, 0.f, 0.f};

  // ---- prologue: slices d0-1 (slot0) and d0 (slot1) ----
  GLOAD(d0 - 1);
  STAGE(); GLOAD(d0); __syncthreads();
  if (is_c) HCONV(0);
  __syncthreads();
  STAGE(); GLOAD(d0 + 1); __syncthreads();
  if (is_c) HCONV(1);
  __syncthreads();

  // ---- main loop, fully unrolled: output slice d0+k ----
#pragma unroll
  for (int k = 0; k < DCHUNK; ++k) {
    STAGE();                               // LDS <- slice d0+1+k (loaded last iter)
    if (k < DCHUNK - 1) GLOAD(d0 + 2 + k); // issue next; consumed next iter top
    __syncthreads();
    const int i0 = k % 3, i1 = (k + 1) % 3, i2 = (k + 2) % 3;
    if (is_c) {
      HCONV(i2);                           // state <- slice d0+1+k
      const v4h gx0 = B[i1][0] * h2 + (B[i0][0] + B[i2][0]);
      const v4h gy0 = C[i1][0] * h2 + (C[i0][0] + C[i2][0]);
      const v4h gz0 = A[i2][0] - A[i0][0];
      const v4h q0h = gx0 * gx0 + gy0 * gy0 + gz0 * gz0;
      const v4h gx1 = B[i1][1] * h2 + (B[i0][1] + B[i2][1]);
      const v4h gy1 = C[i1][1] * h2 + (C[i0][1] + C[i2][1]);
      const v4h gz1 = A[i2][1] - A[i0][1];
      const v4h q1h = gx1 * gx1 + gy1 * gy1 + gz1 * gz1;
      const v4f q0 = __builtin_convertvector(q0h, v4f) + EPS;
      const v4f q1 = __builtin_convertvector(q1h, v4f) + EPS;
      v4f dd_;
#pragma unroll
      for (int j = 0; j < 4; ++j)
        dd_[j] = __builtin_amdgcn_sqrtf(q0[j]) - __builtin_amdgcn_sqrtf(q1[j]);
#pragma unroll
      for (int j = 0; j < 4; ++j) dd_[j] = fabsf(dd_[j]);
      accv += dd_;
    }
    __syncthreads();
  }

  // ---- reduction: wave shfl -> LDS -> one atomic per block ----
  float sred = accv[0] + accv[1] + accv[2] + accv[3];
#pragma unroll
  for (int off = 32; off > 0; off >>= 1) sred += __shfl_down(sred, off, 64);
  __shared__ float wsum[THREADS / 64];
  const int wid = tid >> 6;
  if (lane == 0) wsum[wid] = sred;
  __syncthreads();
  if (tid == 0) {
    float t = 0.f;
#pragma unroll
    for (int i = 0; i < THREADS / 64; ++i) t += wsum[i];
    atomicAdd(out, t * (1.0f / (float)((size_t)Bd * Dd * Hd * Wd)));
  }
}

extern "C" void kernel_launch(void* const* d_in, const int* in_sizes, int n_in,
                              void* d_out, int out_size, void* d_ws, size_t ws_size,
                              hipStream_t stream) {
  const float* pred = (const float*)d_in[0];
  const float* targ = (const float*)d_in[1];
  float* out = (float*)d_out;
  (void)in_sizes; (void)n_in; (void)out_size; (void)d_ws; (void)ws_size;

  hipMemsetAsync(out, 0, sizeof(float), stream);
  dim3 grid(RGROUPS * WSEG, NCHUNK, Bd);
  sobel_loss_kernel<<<grid, THREADS, 0, stream>>>(pred, targ, out);
}

// Round 23
// 38.515 us; speedup vs baseline: 1.3225x; 1.3225x over previous
//
#include <hip/hip_runtime.h>

namespace {
constexpr int Wd = 160, Hd = 192, Dd = 160, Bd = 2;
constexpr int HW = Hd * Wd;
constexpr int THREADS = 256;               // 4 waves
constexpr int ROWS_OUT = 6;                // output rows per block
constexpr int PAIRS = 7;                   // pair-rows ps(0..6) over 8 staged rows
constexpr int RS = 164;                    // fp16 row stride (halves)
constexpr int STRIPS = 40;                 // 4-wide strips per row
constexpr int CTHREADS = ROWS_OUT * STRIPS;   // 240 compute threads
constexpr int STHREADS = 240;              // 3 groups x 2 tensors x 40 strips
constexpr int DCHUNK = 10;                 // grid 1024 (proven best)
constexpr int NCHUNK = Dd / DCHUNK;        // 16
constexpr int RGROUPS = Hd / ROWS_OUT;     // 32
constexpr float EPS = 1e-8f;
}

using v4f = __attribute__((ext_vector_type(4))) float;
using v4h = __attribute__((ext_vector_type(4))) _Float16;

__device__ __forceinline__ float dpp_up1(float v) {   // lane i <- lane i-1
  return __int_as_float(__builtin_amdgcn_update_dpp(
      0, __float_as_int(v), 0x138, 0xF, 0xF, true));  // wave_shr:1
}
__device__ __forceinline__ float dpp_dn1(float v) {   // lane i <- lane i+1
  return __int_as_float(__builtin_amdgcn_update_dpp(
      0, __float_as_int(v), 0x130, 0xF, 0xF, true));  // wave_shl:1
}

__global__ __launch_bounds__(THREADS) void sobel_loss_kernel(
    const float* __restrict__ pred, const float* __restrict__ targ,
    float* __restrict__ out) {
  // staged PAIR-SUMS of separable row partials (Sh=[1,2,1] factorization):
  //   ps(r) = sw(r)+sw(r+1), pd(r) = dw(r)+dw(r+1); A=ps(cr)+ps(cr+1),
  //   B=pd(cr)+pd(cr+1), C=ps(cr+1)-ps(cr)  -> 4 reads/tensor instead of 6.
  __shared__ __align__(16) _Float16 lps[2][PAIRS][RS];   // 4.6 KB
  __shared__ __align__(16) _Float16 lpd[2][PAIRS][RS];   // 4.6 KB
  const int tid = threadIdx.x;
  const int lane = tid & 63;
  const int h0 = blockIdx.x * ROWS_OUT;
  const int d0 = blockIdx.y * DCHUNK;
  const size_t volOff = (size_t)blockIdx.z * Dd * HW;
  const float* pb = pred + volOff;
  const float* tb = targ + volOff;

  // ---- staging decode: group g (rows 2g..2g+2 or 2g..2g+3), tensor, strip --
  const int g = tid / 80;                  // 0..2 for staging threads
  const int q = tid - g * 80;
  const int t_ = q / 40;
  const int s = q - t_ * 40;
  const bool is_s = (tid < STHREADS);
  const int r0 = 2 * g;                    // first staged row of this group
  const int nr = (g < 2) ? 3 : 4;          // rows loaded by this thread
  const int np = (g < 2) ? 2 : 3;          // pairs produced

  const float* gsj[4];
  bool rvj[4];
#pragma unroll
  for (int j = 0; j < 4; ++j) {
    const int hh = h0 - 1 + r0 + j;        // global row of staged index r0+j
    const bool jn = is_s && (j < nr);
    rvj[j] = jn && ((unsigned)hh < (unsigned)Hd);
    gsj[j] = (t_ ? tb : pb) + (size_t)(rvj[j] ? hh : 0) * Wd + s * 4;
  }
  const bool zL = (s == 0), zR = (s == STRIPS - 1);
  const bool pL = is_s && (lane == 0) && !zL;
  const bool pR = is_s && (lane == 63) && !zR;

  _Float16* pps[3];
  _Float16* ppd[3];
  bool pok[3];
#pragma unroll
  for (int p = 0; p < 3; ++p) {
    pok[p] = is_s && (p < np);
    const int pr = pok[p] ? (r0 + p) : 0;  // pair-rows disjoint across groups
    pps[p] = &lps[t_][pr][s * 4];
    ppd[p] = &lpd[t_][pr][s * 4];
  }

  float4 m[4];
  float hl[4], hr[4];
  auto GLOAD = [&](int d) {   // coalesced float4 rows + exec-masked edge scalars
    const bool dok = (unsigned)d < (unsigned)Dd;
    const size_t so = (size_t)d * HW;
#pragma unroll
    for (int j = 0; j < 4; ++j) {
      float4 v = make_float4(0.f, 0.f, 0.f, 0.f);
      float a = 0.f, b = 0.f;
      if (dok && rvj[j]) {
        v = *reinterpret_cast<const float4*>(gsj[j] + so);
        if (pL) a = gsj[j][so - 1];
        if (pR) b = gsj[j][so + 4];
      }
      m[j] = v; hl[j] = a; hr[j] = b;
    }
  };

  auto STAGE = [&]() {   // w-conv rows in f32, pair-sum, write fp16 ps/pd
    v4f swf[4], dwf[4];
#pragma unroll
    for (int j = 0; j < 4; ++j) {
      float xl = dpp_up1(m[j].w);          // lane-1 = strip s-1 of same row
      float xr = dpp_dn1(m[j].x);
      if (zL) xl = 0.f;
      if (pL) xl = hl[j];
      if (zR) xr = 0.f;
      if (pR) xr = hr[j];
      const float x0 = xl, x1 = m[j].x, x2 = m[j].y, x3 = m[j].z,
                  x4 = m[j].w, x5 = xr;
      swf[j][0] = fmaf(2.f, x1, x0 + x2);  dwf[j][0] = x2 - x0;
      swf[j][1] = fmaf(2.f, x2, x1 + x3);  dwf[j][1] = x3 - x1;
      swf[j][2] = fmaf(2.f, x3, x2 + x4);  dwf[j][2] = x4 - x2;
      swf[j][3] = fmaf(2.f, x4, x3 + x5);  dwf[j][3] = x5 - x3;
    }
#pragma unroll
    for (int p = 0; p < 3; ++p) {
      if (pok[p]) {
        const v4f psv = swf[p] + swf[p + 1];
        const v4f pdv = dwf[p] + dwf[p + 1];
        *reinterpret_cast<v4h*>(pps[p]) = __builtin_convertvector(psv, v4h);
        *reinterpret_cast<v4h*>(ppd[p]) = __builtin_convertvector(pdv, v4h);
      }
    }
  };

  // ---- compute decode: output row cr (0..5), strip cs (0..39) ----
  const int cr = tid / STRIPS;
  const int cs4 = (tid - cr * STRIPS) * 4;
  const bool is_c = (tid < CTHREADS);

  // rolling state [slot][tensor] as packed fp16 -> v_pk_*_f16 math
  v4h A[3][2], B[3][2], C[3][2];

  auto HCONV = [&](int slot) {   // 4 b64 reads + 3 pk ops per tensor
#pragma unroll
    for (int tt = 0; tt < 2; ++tt) {
      const v4h pa = *reinterpret_cast<const v4h*>(&lps[tt][cr][cs4]);
      const v4h pb2 = *reinterpret_cast<const v4h*>(&lps[tt][cr + 1][cs4]);
      const v4h da = *reinterpret_cast<const v4h*>(&lpd[tt][cr][cs4]);
      const v4h db = *reinterpret_cast<const v4h*>(&lpd[tt][cr + 1][cs4]);
      A[slot][tt] = pa + pb2;
      B[slot][tt] = da + db;
      C[slot][tt] = pb2 - pa;
    }
  };

  v4f accv = {0.f, 0.f, 0.f, 0.f};
  const _Float16 h2 = (_Float16)2.0f;

  // ---- prologue: slices d0-1 (slot0) and d0 (slot1) ----
  GLOAD(d0 - 1);
  STAGE(); GLOAD(d0); __syncthreads();
  if (is_c) HCONV(0);
  __syncthreads();
  STAGE(); GLOAD(d0 + 1); __syncthreads();
  if (is_c) HCONV(1);
  __syncthreads();

  // ---- main loop, fully unrolled: output slice d0+k ----
#pragma unroll
  for (int k = 0; k < DCHUNK; ++k) {
    STAGE();                               // LDS <- slice d0+1+k (loaded last iter)
    if (k < DCHUNK - 1) GLOAD(d0 + 2 + k); // issue next; consumed next iter top
    __syncthreads();
    const int i0 = k % 3, i1 = (k + 1) % 3, i2 = (k + 2) % 3;
    if (is_c) {
      HCONV(i2);                           // state <- slice d0+1+k
      const v4h gx0 = B[i1][0] * h2 + (B[i0][0] + B[i2][0]);
      const v4h gy0 = C[i1][0] * h2 + (C[i0][0] + C[i2][0]);
      const v4h gz0 = A[i2][0] - A[i0][0];
      const v4h q0h = gx0 * gx0 + gy0 * gy0 + gz0 * gz0;
      const v4h gx1 = B[i1][1] * h2 + (B[i0][1] + B[i2][1]);
      const v4h gy1 = C[i1][1] * h2 + (C[i0][1] + C[i2][1]);
      const v4h gz1 = A[i2][1] - A[i0][1];
      const v4h q1h = gx1 * gx1 + gy1 * gy1 + gz1 * gz1;
      const v4f q0 = __builtin_convertvector(q0h, v4f) + EPS;
      const v4f q1 = __builtin_convertvector(q1h, v4f) + EPS;
      v4f dd_;
#pragma unroll
      for (int j = 0; j < 4; ++j)
        dd_[j] = __builtin_amdgcn_sqrtf(q0[j]) - __builtin_amdgcn_sqrtf(q1[j]);
#pragma unroll
      for (int j = 0; j < 4; ++j) dd_[j] = fabsf(dd_[j]);
      accv += dd_;
    }
    __syncthreads();
  }

  // ---- reduction: wave shfl -> LDS -> one atomic per block ----
  float sred = accv[0] + accv[1] + accv[2] + accv[3];
#pragma unroll
  for (int off = 32; off > 0; off >>= 1) sred += __shfl_down(sred, off, 64);
  __shared__ float wsum[THREADS / 64];
  const int wid = tid >> 6;
  if (lane == 0) wsum[wid] = sred;
  __syncthreads();
  if (tid == 0) {
    float t = 0.f;
#pragma unroll
    for (int i = 0; i < THREADS / 64; ++i) t += wsum[i];
    atomicAdd(out, t * (1.0f / (float)((size_t)Bd * Dd * Hd * Wd)));
  }
}

extern "C" void kernel_launch(void* const* d_in, const int* in_sizes, int n_in,
                              void* d_out, int out_size, void* d_ws, size_t ws_size,
                              hipStream_t stream) {
  const float* pred = (const float*)d_in[0];
  const float* targ = (const float*)d_in[1];
  float* out = (float*)d_out;
  (void)in_sizes; (void)n_in; (void)out_size; (void)d_ws; (void)ws_size;

  hipMemsetAsync(out, 0, sizeof(float), stream);
  dim3 grid(RGROUPS, NCHUNK, Bd);
  sobel_loss_kernel<<<grid, THREADS, 0, stream>>>(pred, targ, out);
}

// Round 24
// 35.748 us; speedup vs baseline: 1.4248x; 1.0774x over previous
//
#include <hip/hip_runtime.h>

namespace {
constexpr int Wd = 160, Hd = 192, Dd = 160, Bd = 2;
constexpr int HW = Hd * Wd;
constexpr int THREADS = 256;               // 4 waves
constexpr int ROWS_OUT = 6;                // output rows per block
constexpr int ROWS_LDS = 8;                // staged rows incl. h-halo
constexpr int RS = 164;                    // fp16 row stride (halves)
constexpr int STRIPS = 40;                 // 4-wide strips per row
constexpr int CTHREADS = ROWS_OUT * STRIPS;   // 240 compute threads
constexpr int TASKS = 2 * ROWS_LDS * STRIPS;  // 640 staging tasks
constexpr int DCHUNK = 10;                 // grid 1024 (proven best)
constexpr int NCHUNK = Dd / DCHUNK;        // 16
constexpr int RGROUPS = Hd / ROWS_OUT;     // 32
constexpr int BUFSTRIDE = 2 * ROWS_LDS * RS;  // halves between double buffers
constexpr float EPS = 1e-8f;
}

using v4f = __attribute__((ext_vector_type(4))) float;
using v4h = __attribute__((ext_vector_type(4))) _Float16;

__device__ __forceinline__ float dpp_up1(float v) {   // lane i <- lane i-1
  return __int_as_float(__builtin_amdgcn_update_dpp(
      0, __float_as_int(v), 0x138, 0xF, 0xF, true));  // wave_shr:1
}
__device__ __forceinline__ float dpp_dn1(float v) {   // lane i <- lane i+1
  return __int_as_float(__builtin_amdgcn_update_dpp(
      0, __float_as_int(v), 0x130, 0xF, 0xF, true));  // wave_shl:1
}

__global__ __launch_bounds__(THREADS) void sobel_loss_kernel(
    const float* __restrict__ pred, const float* __restrict__ targ,
    float* __restrict__ out) {
  // double-buffered fp16 row partials: [buf][tensor][row][RS], 20.5 KB total
  __shared__ __align__(16) _Float16 lsw[2][2][ROWS_LDS][RS];
  __shared__ __align__(16) _Float16 ldw[2][2][ROWS_LDS][RS];
  const int tid = threadIdx.x;
  const int lane = tid & 63;
  const int h0 = blockIdx.x * ROWS_OUT;
  const int d0 = blockIdx.y * DCHUNK;
  const size_t volOff = (size_t)blockIdx.z * Dd * HW;
  const float* pb = pred + volOff;
  const float* tb = targ + volOff;

  // ---- staging task decode (2.5 tasks/thread, loop-invariant) ----
  const float* gs[3];
  _Float16* psw[3];
  _Float16* pdw[3];
  bool sok[3], rok[3], zL[3], zR[3], pL[3], pR[3];
#pragma unroll
  for (int u = 0; u < 3; ++u) {
    const int i = tid + 256 * u;
    const bool ok = (i < TASKS);
    const int ic = ok ? i : 0;
    const int t_ = ic / (ROWS_LDS * STRIPS);
    const int rem = ic - t_ * (ROWS_LDS * STRIPS);
    const int r8 = rem / STRIPS, s = rem - r8 * STRIPS;
    const int hh = h0 - 1 + r8;
    const bool rv = ok && ((unsigned)hh < (unsigned)Hd);
    sok[u] = ok;
    rok[u] = rv;
    zL[u] = (s == 0);
    zR[u] = (s == STRIPS - 1);
    pL[u] = ok && (lane == 0) && (s != 0);
    pR[u] = ok && (lane == 63) && (s != STRIPS - 1);
    gs[u] = (t_ ? tb : pb) + (size_t)(rv ? hh : 0) * Wd + s * 4;
    psw[u] = &lsw[0][t_][r8][s * 4];
    pdw[u] = &ldw[0][t_][r8][s * 4];
  }

  // two prefetch register sets (A = even-parity slice, B = odd-parity slice)
  float4 mA[3], mB[3];
  float hlA[3], hrA[3], hlB[3], hrB[3];

  auto GLOADto = [&](int d, float4 (&m)[3], float (&hl)[3], float (&hr)[3]) {
    const bool dok = (unsigned)d < (unsigned)Dd;
    const size_t so = (size_t)d * HW;
#pragma unroll
    for (int u = 0; u < 3; ++u) {
      float4 v = make_float4(0.f, 0.f, 0.f, 0.f);
      float a = 0.f, b = 0.f;
      if (dok && rok[u]) {
        v = *reinterpret_cast<const float4*>(gs[u] + so);
        if (pL[u]) a = gs[u][so - 1];
        if (pR[u]) b = gs[u][so + 4];
      }
      m[u] = v; hl[u] = a; hr[u] = b;
    }
  };

  auto STAGEfrom = [&](int b, const float4 (&m)[3], const float (&hl)[3],
                       const float (&hr)[3]) {
#pragma unroll
    for (int u = 0; u < 3; ++u) {
      float xl = dpp_up1(m[u].w);          // lane-1 holds x[4s-4..4s-1]
      float xr = dpp_dn1(m[u].x);          // lane+1 holds x[4s+4..4s+7]
      if (zL[u]) xl = 0.f;
      if (pL[u]) xl = hl[u];
      if (zR[u]) xr = 0.f;
      if (pR[u]) xr = hr[u];
      const float x0 = xl, x1 = m[u].x, x2 = m[u].y, x3 = m[u].z,
                  x4 = m[u].w, x5 = xr;
      v4f swf, dwf;
      swf[0] = fmaf(2.f, x1, x0 + x2);  dwf[0] = x2 - x0;
      swf[1] = fmaf(2.f, x2, x1 + x3);  dwf[1] = x3 - x1;
      swf[2] = fmaf(2.f, x3, x2 + x4);  dwf[2] = x4 - x2;
      swf[3] = fmaf(2.f, x4, x3 + x5);  dwf[3] = x5 - x3;
      if (sok[u]) {
        *reinterpret_cast<v4h*>(psw[u] + b * BUFSTRIDE) =
            __builtin_convertvector(swf, v4h);
        *reinterpret_cast<v4h*>(pdw[u] + b * BUFSTRIDE) =
            __builtin_convertvector(dwf, v4h);
      }
    }
  };

  // ---- compute decode: output row cr (0..5), strip cs (0..39) ----
  const int cr = tid / STRIPS;
  const int cs4 = (tid - cr * STRIPS) * 4;
  const bool is_c = (tid < CTHREADS);

  // rolling state [slot][tensor] as packed fp16 -> v_pk_*_f16 math
  v4h A[3][2], B[3][2], C[3][2];
  const _Float16 h2 = (_Float16)2.0f;

  auto HCONV = [&](int slot, int b) {
#pragma unroll
    for (int t_ = 0; t_ < 2; ++t_) {
      const v4h sm = *reinterpret_cast<const v4h*>(&lsw[b][t_][cr][cs4]);
      const v4h s0 = *reinterpret_cast<const v4h*>(&lsw[b][t_][cr + 1][cs4]);
      const v4h sp = *reinterpret_cast<const v4h*>(&lsw[b][t_][cr + 2][cs4]);
      const v4h dm = *reinterpret_cast<const v4h*>(&ldw[b][t_][cr][cs4]);
      const v4h dd = *reinterpret_cast<const v4h*>(&ldw[b][t_][cr + 1][cs4]);
      const v4h dp = *reinterpret_cast<const v4h*>(&ldw[b][t_][cr + 2][cs4]);
      A[slot][t_] = s0 * h2 + (sm + sp);
      B[slot][t_] = dd * h2 + (dm + dp);
      C[slot][t_] = sp - sm;
    }
  };

  v4f accv = {0.f, 0.f, 0.f, 0.f};

  auto EMIT = [&](int i0, int i1, int i2) {
    const v4h gx0 = B[i1][0] * h2 + (B[i0][0] + B[i2][0]);
    const v4h gy0 = C[i1][0] * h2 + (C[i0][0] + C[i2][0]);
    const v4h gz0 = A[i2][0] - A[i0][0];
    const v4h q0h = gx0 * gx0 + gy0 * gy0 + gz0 * gz0;
    const v4h gx1 = B[i1][1] * h2 + (B[i0][1] + B[i2][1]);
    const v4h gy1 = C[i1][1] * h2 + (C[i0][1] + C[i2][1]);
    const v4h gz1 = A[i2][1] - A[i0][1];
    const v4h q1h = gx1 * gx1 + gy1 * gy1 + gz1 * gz1;
    const v4f q0 = __builtin_convertvector(q0h, v4f) + EPS;
    const v4f q1 = __builtin_convertvector(q1h, v4f) + EPS;
    v4f dd_;
#pragma unroll
    for (int j = 0; j < 4; ++j)
      dd_[j] = __builtin_amdgcn_sqrtf(q0[j]) - __builtin_amdgcn_sqrtf(q1[j]);
#pragma unroll
    for (int j = 0; j < 4; ++j) dd_[j] = fabsf(dd_[j]);
    accv += dd_;
  };

  // ---- prologue: pair 0 = slices d0-1 (bufA, slot0), d0 (bufB, slot1) ----
  GLOADto(d0 - 1, mA, hlA, hrA);
  GLOADto(d0,     mB, hlB, hrB);
  STAGEfrom(0, mA, hlA, hrA);
  STAGEfrom(1, mB, hlB, hrB);
  GLOADto(d0 + 1, mA, hlA, hrA);          // pair-1 loads, covered by HCONVs
  GLOADto(d0 + 2, mB, hlB, hrB);
  __syncthreads();
  if (is_c) { HCONV(0, 0); HCONV(1, 1); } // absorb d0-1, d0 (no emit)
  __syncthreads();

  // ---- main loop: pair j = slices d0-1+2j (bufA), d0+2j (bufB);
  //      2 slices per barrier period (12 periods/chunk vs 22) ----
#pragma unroll
  for (int j = 1; j <= DCHUNK / 2; ++j) {
    STAGEfrom(0, mA, hlA, hrA);           // bufA <- slice d0-1+2j
    STAGEfrom(1, mB, hlB, hrB);           // bufB <- slice d0+2j
    if (j < DCHUNK / 2) {
      GLOADto(d0 + 1 + 2 * j, mA, hlA, hrA);
      GLOADto(d0 + 2 + 2 * j, mB, hlB, hrB);
    }
    __syncthreads();
    if (is_c) {
      const int na = 2 * j;               // slot index of slice d0-1+2j
      HCONV(na % 3, 0);                   // absorb even-parity slice
      EMIT((na + 1) % 3, (na + 2) % 3, na % 3);          // emit d0-2+2j
      const int nb = 2 * j + 1;           // slot index of slice d0+2j
      HCONV(nb % 3, 1);                   // absorb odd-parity slice
      EMIT((nb + 1) % 3, (nb + 2) % 3, nb % 3);          // emit d0-1+2j
    }
    __syncthreads();
  }

  // ---- reduction: wave shfl -> LDS -> one atomic per block ----
  float sred = accv[0] + accv[1] + accv[2] + accv[3];
#pragma unroll
  for (int off = 32; off > 0; off >>= 1) sred += __shfl_down(sred, off, 64);
  __shared__ float wsum[THREADS / 64];
  const int wid = tid >> 6;
  if (lane == 0) wsum[wid] = sred;
  __syncthreads();
  if (tid == 0) {
    float t = 0.f;
#pragma unroll
    for (int i = 0; i < THREADS / 64; ++i) t += wsum[i];
    atomicAdd(out, t * (1.0f / (float)((size_t)Bd * Dd * Hd * Wd)));
  }
}

extern "C" void kernel_launch(void* const* d_in, const int* in_sizes, int n_in,
                              void* d_out, int out_size, void* d_ws, size_t ws_size,
                              hipStream_t stream) {
  const float* pred = (const float*)d_in[0];
  const float* targ = (const float*)d_in[1];
  float* out = (float*)d_out;
  (void)in_sizes; (void)n_in; (void)out_size; (void)d_ws; (void)ws_size;

  hipMemsetAsync(out, 0, sizeof(float), stream);
  dim3 grid(RGROUPS, NCHUNK, Bd);
  sobel_loss_kernel<<<grid, THREADS, 0, stream>>>(pred, targ, out);
}